// Round 20
// baseline (44.128 us; speedup 1.0000x reference)
//
#include <hip/hip_runtime.h>
#include <stdint.h>

typedef unsigned short u16;
typedef __attribute__((ext_vector_type(8))) short short8;
typedef __attribute__((ext_vector_type(4))) float f32x4;
typedef __attribute__((ext_vector_type(16))) float f32x16;

#define B_ 8
#define T_ 2048
#define C_ 1024
#define D_ 64
#define PSC 0.04508422f  /* C^-0.5 * log2(e) */

__device__ inline uint32_t pack2(float lo, float hi) {
  uint32_t r;
  asm("v_cvt_pk_bf16_f32 %0, %1, %2" : "=v"(r) : "v"(lo), "v"(hi));
  return r;
}
__device__ inline u16 f2bf(float f) {
  uint32_t r;
  asm("v_cvt_pk_bf16_f32 %0, %1, %2" : "=v"(r) : "v"(f), "v"(f));
  return (u16)r;
}

// ---------------- kernel 0: W [1024][64] f32 -> B-fragment-order bf16 ------
__global__ __launch_bounds__(256) void wt_kernel(const float* __restrict__ Wq,
                                                 const float* __restrict__ Wk,
                                                 const float* __restrict__ Wv,
                                                 u16* __restrict__ wfrag) {
  const int mi = blockIdx.x >> 4;
  const int k0 = (blockIdx.x & 15) * 64;
  const float* W = (mi == 0) ? Wq : ((mi == 1) ? Wk : Wv);
  const float sc = (mi == 0) ? PSC : 1.0f;
  __shared__ u16 tr[64 * 68];

  const int t = threadIdx.x;
  {
    const int n = t & 63, kr0 = (t >> 6) * 16;
#pragma unroll
    for (int j = 0; j < 16; ++j)
      tr[n * 68 + kr0 + j] = f2bf(W[(size_t)(k0 + kr0 + j) * 64 + n] * sc);
  }
  __syncthreads();
  {
    const int n = t >> 2, q16 = (t & 3) * 16;
    const int n16g = mi * 4 + (n >> 4);
#pragma unroll
    for (int h = 0; h < 2; ++h) {
      const int kr = q16 + h * 8;
      const int kchunk = (k0 + kr) >> 5;
      const int lane = (n & 15) + 16 * ((kr >> 3) & 3);
      uint32_t pk[4];
#pragma unroll
      for (int jj = 0; jj < 4; ++jj)
        pk[jj] = (uint32_t)tr[n * 68 + kr + 2 * jj] | ((uint32_t)tr[n * 68 + kr + 2 * jj + 1] << 16);
      *(uint4*)&wfrag[(((size_t)n16g * 32 + kchunk) * 64 + lane) * 8] = *(uint4*)&pk[0];
    }
  }
}

// ---------------- kernel A: QKV projection, BM=64, register-held W ---------
__global__ __launch_bounds__(512, 1) void qkv_kernel(const float* __restrict__ x,
                                                     const u16* __restrict__ wfrag,
                                                     u16* __restrict__ qfr,
                                                     u16* __restrict__ kfr,
                                                     u16* __restrict__ vfr) {
  __shared__ __align__(16) u16 xl[2][64 * 64];  // 2 x 8 KB

  const int tid = threadIdx.x;
  const int w = tid >> 6, l = tid & 63;
  const int lo16 = l & 15, hi4 = l >> 4;
  const int wh = w & 1, ng = w >> 1;
  const int m0 = blockIdx.x * 64;

  const int xrow = tid >> 3;        // 0..63
  const int xc8 = tid & 7;
  const float* xs0 = x + (size_t)(m0 + xrow) * C_ + xc8 * 8;
  u16* xdst0 = &xl[0][xrow * 64 + ((xc8 ^ (xrow & 7)) << 3)];
  u16* xdst1 = &xl[1][xrow * 64 + ((xc8 ^ (xrow & 7)) << 3)];

  f32x4 acc[2][3];
#pragma unroll
  for (int rf = 0; rf < 2; ++rf)
#pragma unroll
    for (int j = 0; j < 3; ++j) acc[rf][j] = {0.f, 0.f, 0.f, 0.f};

  const u16* wbase = wfrag + (size_t)(ng * 3) * 32 * 512 + l * 8;
  short8 wA[6], wB[6];
  float4 xr1a, xr1b, xr2a, xr2b;

#define LOADW(DST, KT)                                                        \
  _Pragma("unroll")                                                           \
  for (int i = 0; i < 6; ++i)                                                 \
    DST[i] = *(const short8*)(wbase + ((i >> 1) * 32 + (KT) * 2 + (i & 1)) * 512);

#define PACKX(A0, A1, DST)                                                    \
  { uint32_t p[4] = {pack2(A0.x, A0.y), pack2(A0.z, A0.w),                    \
                     pack2(A1.x, A1.y), pack2(A1.z, A1.w)};                   \
    *(uint4*)DST = *(uint4*)&p[0]; }

#define MFMA6(XR, WC)                                                         \
  _Pragma("unroll")                                                           \
  for (int k32 = 0; k32 < 2; ++k32) {                                         \
    const int ac = k32 * 4 + hi4;                                             \
    _Pragma("unroll")                                                         \
    for (int rf = 0; rf < 2; ++rf) {                                          \
      const int arow = wh * 32 + rf * 16 + lo16;                              \
      short8 a = *(const short8*)&XR[arow * 64 + ((ac ^ (arow & 7)) << 3)];   \
      _Pragma("unroll")                                                       \
      for (int j = 0; j < 3; ++j)                                             \
        acc[rf][j] = __builtin_amdgcn_mfma_f32_16x16x32_bf16(a, WC[j * 2 + k32], acc[rf][j], 0, 0, 0); \
    }                                                                         \
  }

  {
    float4 f0 = *(const float4*)(xs0 + 0);
    float4 f1 = *(const float4*)(xs0 + 4);
    PACKX(f0, f1, xdst0)
    xr1a = *(const float4*)(xs0 + 64);
    xr1b = *(const float4*)(xs0 + 68);
    LOADW(wA, 0)
  }
  __syncthreads();

#pragma unroll 1
  for (int kt = 0; kt < 14; kt += 2) {
    xr2a = *(const float4*)(xs0 + (kt + 2) * 64);
    xr2b = *(const float4*)(xs0 + (kt + 2) * 64 + 4);
    LOADW(wB, kt + 1)
    MFMA6(xl[0], wA)
    PACKX(xr1a, xr1b, xdst1)
    __syncthreads();
    xr1a = *(const float4*)(xs0 + (kt + 3) * 64);
    xr1b = *(const float4*)(xs0 + (kt + 3) * 64 + 4);
    LOADW(wA, kt + 2)
    MFMA6(xl[1], wB)
    PACKX(xr2a, xr2b, xdst0)
    __syncthreads();
  }
  LOADW(wB, 15)
  MFMA6(xl[0], wA)
  PACKX(xr1a, xr1b, xdst1)
  __syncthreads();
  MFMA6(xl[1], wB)
#undef LOADW
#undef PACKX
#undef MFMA6

  const int bb = m0 >> 11;
  const int tok_b = m0 & 2047;
#pragma unroll
  for (int rf = 0; rf < 2; ++rf) {
    const int row0 = wh * 32 + rf * 16 + hi4 * 4;
    const int tok0 = tok_b + row0;
    const int tt = tok0 >> 6;
    const int t32 = tok0 >> 5;
#pragma unroll
    for (int j = 0; j < 3; ++j) {
      const int cb = ng * 48 + j * 16;
      const int mt = cb >> 6;
      const int col = (cb & 63) + lo16;
      if (mt == 0) {
        const int cs = col >> 4;
        const int lane0 = (tok0 & 31) + 32 * ((col >> 3) & 1);
        u16* qp = qfr + ((((size_t)bb * 64 + t32) * 4 + cs) * 64 + lane0) * 8 + (col & 7);
#pragma unroll
        for (int r = 0; r < 4; ++r) qp[(size_t)r * 8] = f2bf(acc[rf][j][r]);
      } else if (mt == 1) {
        const int h = (tok0 >> 5) & 1;
        const int cs = col >> 4;
        const int lane0 = (tok0 & 31) + 32 * ((col >> 3) & 1);
        u16* kp = kfr + (((((size_t)bb * 32 + tt) * 2 + h) * 4 + cs) * 64 + lane0) * 8 + (col & 7);
#pragma unroll
        for (int r = 0; r < 4; ++r) kp[(size_t)r * 8] = f2bf(acc[rf][j][r]);
      } else {
        const int ks = (tok0 >> 4) & 3;
        const int hi = (tok0 >> 3) & 1;
        const int jj = tok0 & 7;
        const int lane = (col & 31) + 32 * hi;
        const int df = col >> 5;
        uint2 st = {pack2(acc[rf][j][0], acc[rf][j][1]), pack2(acc[rf][j][2], acc[rf][j][3])};
        *(uint2*)&vfr[((((((size_t)bb * 32 + tt) * 4 + ks) * 2 + df) * 64 + lane) * 8 + jj)] = st;
      }
    }
  }
}

// ---------------- kernel B: causal flash attention, D-half split -----------
// grid (8, 128): dh = y>>6 selects 32 output dims; yy = y&63 -> constant-sum
// qt pairing. Both dh-halves do identical NT (no idle waves). O accumulator
// and V fragments halved -> lower VGPR peak -> higher occupancy.
__global__ __launch_bounds__(256, 2) void attn_kernel(const u16* __restrict__ qfr,
                                                      const u16* __restrict__ kfr,
                                                      const u16* __restrict__ vfr,
                                                      float* __restrict__ out) {
  __shared__ float o_lds[4][32][36];
  __shared__ float l_lds[4][64];

  const int tid = threadIdx.x;
  const int w = tid >> 6, l = tid & 63;
  const int l31 = l & 31, hi1 = l >> 5;
  const int b = blockIdx.x;
  const int y = blockIdx.y;
  const int dh = y >> 6;
  const int yy = y & 63;
  const int qt = (yy < 32) ? (63 - 2 * yy) : (2 * (yy - 32));
  const int qbase = qt * 32;
  const int boff = b * T_;
  const int NT = (qt + 2) >> 1;

  short8 qf[4];
  {
    const u16* qp = qfr + (size_t)(b * 64 + qt) * 4 * 512 + l * 8;
#pragma unroll
    for (int cs = 0; cs < 4; ++cs) qf[cs] = *(const short8*)(qp + cs * 512);
  }

  const u16* kfb = kfr + (size_t)b * 32 * 4096 + l * 8;
  const u16* vfb = vfr + (size_t)b * 32 * 4096 + l * 8 + dh * 512;

  f32x16 O0;
#pragma unroll
  for (int r = 0; r < 16; ++r) O0[r] = 0.f;
  float lsum = 0.f;

  short8 kf[2][4];
#define LOADK(T) { const u16* kp = kfb + (size_t)(T) * 4096; \
  _Pragma("unroll") for (int h2 = 0; h2 < 2; ++h2) \
  _Pragma("unroll") for (int cs = 0; cs < 4; ++cs) \
    kf[h2][cs] = *(const short8*)(kp + (h2 * 4 + cs) * 512); }

  if (w < NT) LOADK(w);

  union { uint32_t u[4]; short8 v; } pu;
  short8 pa[4];

#pragma unroll 1
  for (int t = w; t < NT; t += 4) {
    const int k0 = t * 64;

    short8 vf[4];
    {
      const u16* vp = vfb + (size_t)t * 4096;
#pragma unroll
      for (int ks = 0; ks < 4; ++ks)
        vf[ks] = *(const short8*)(vp + ks * 1024);
    }

    f32x16 s0, s1, s0b, s1b;
#pragma unroll
    for (int r = 0; r < 16; ++r) { s0[r] = 0.f; s1[r] = 0.f; s0b[r] = 0.f; s1b[r] = 0.f; }
    __builtin_amdgcn_s_setprio(1);
#pragma unroll
    for (int cs = 0; cs < 2; ++cs) {
      s0 = __builtin_amdgcn_mfma_f32_32x32x16_bf16(kf[0][cs], qf[cs], s0, 0, 0, 0);
      s1 = __builtin_amdgcn_mfma_f32_32x32x16_bf16(kf[1][cs], qf[cs], s1, 0, 0, 0);
      s0b = __builtin_amdgcn_mfma_f32_32x32x16_bf16(kf[0][cs + 2], qf[cs + 2], s0b, 0, 0, 0);
      s1b = __builtin_amdgcn_mfma_f32_32x32x16_bf16(kf[1][cs + 2], qf[cs + 2], s1b, 0, 0, 0);
    }
    __builtin_amdgcn_s_setprio(0);
#pragma unroll
    for (int r = 0; r < 16; ++r) { s0[r] += s0b[r]; s1[r] += s1b[r]; }

    if (t + 4 < NT) LOADK(t + 4);

    if (k0 + 63 > qbase) {
#pragma unroll
      for (int r = 0; r < 16; ++r) {
        const int kr = (r & 3) + 8 * (r >> 2) + 4 * hi1;
        if (k0 + kr > qbase + l31) s0[r] = -1e30f;
        if (k0 + 32 + kr > qbase + l31) s1[r] = -1e30f;
      }
    }

    float p0[16], p1[16];
    float ts[4] = {0.f, 0.f, 0.f, 0.f};
#pragma unroll
    for (int r = 0; r < 16; ++r) {
      p0[r] = exp2f(s0[r]);
      p1[r] = exp2f(s1[r]);
      ts[r & 3] += p0[r] + p1[r];
    }
    lsum += (ts[0] + ts[1]) + (ts[2] + ts[3]);

#define REDIST(KS, ARR) { \
    const int s8 = ((KS) & 1) * 8; \
    uint32_t c0a = pack2(ARR[s8 + 0], ARR[s8 + 1]); \
    uint32_t c0b = pack2(ARR[s8 + 2], ARR[s8 + 3]); \
    uint32_t c1a = pack2(ARR[s8 + 4], ARR[s8 + 5]); \
    uint32_t c1b = pack2(ARR[s8 + 6], ARR[s8 + 7]); \
    uint32_t fa = hi1 ? c0a : c1a; \
    uint32_t fb = hi1 ? c0b : c1b; \
    uint32_t ga = __shfl_xor(fa, 32); \
    uint32_t gb = __shfl_xor(fb, 32); \
    pu.u[0] = hi1 ? ga : c0a; \
    pu.u[1] = hi1 ? gb : c0b; \
    pu.u[2] = hi1 ? c1a : ga; \
    pu.u[3] = hi1 ? c1b : gb; \
    pa[KS] = pu.v; }
    REDIST(0, p0)
    REDIST(1, p0)
    REDIST(2, p1)
    REDIST(3, p1)
#undef REDIST

    __builtin_amdgcn_s_setprio(1);
#pragma unroll
    for (int ks = 0; ks < 4; ++ks)
      O0 = __builtin_amdgcn_mfma_f32_32x32x16_bf16(pa[ks], vf[ks], O0, 0, 0, 0);
    __builtin_amdgcn_s_setprio(0);
  }
#undef LOADK

#pragma unroll
  for (int r = 0; r < 16; ++r) {
    const int qr = (r & 3) + 8 * (r >> 2) + 4 * hi1;
    o_lds[w][qr][l31] = O0[r];
  }
  l_lds[w][l] = lsum;
  __syncthreads();

  // combine 4 segments over this block's 32 dims, normalize, write f32
  {
    const int q = tid >> 3;          // 0..31
    const int dc = (tid & 7) * 4;    // 0..28
    float lacc = 0.f;
    float oacc[4] = {0.f, 0.f, 0.f, 0.f};
#pragma unroll
    for (int s = 0; s < 4; ++s) {
      lacc += l_lds[s][q] + l_lds[s][q + 32];
#pragma unroll
      for (int j = 0; j < 4; ++j) oacc[j] += o_lds[s][q][dc + j];
    }
    const float inv = 1.f / lacc;
    float4 r0 = {oacc[0] * inv, oacc[1] * inv, oacc[2] * inv, oacc[3] * inv};
    *(float4*)&out[(size_t)(boff + qbase + q) * 64 + dh * 32 + dc] = r0;
  }
}

extern "C" void kernel_launch(void* const* d_in, const int* in_sizes, int n_in,
                              void* d_out, int out_size, void* d_ws, size_t ws_size,
                              hipStream_t stream) {
  const float* x  = (const float*)d_in[0];
  const float* Wq = (const float*)d_in[1];
  const float* Wk = (const float*)d_in[2];
  const float* Wv = (const float*)d_in[3];
  float* out = (float*)d_out;

  u16* ws    = (u16*)d_ws;
  u16* wfrag = ws;                      // [12][32][64][8] (Wq slice PSC-scaled)
  u16* qfr   = ws + 196608;             // [8][64][4][64][8]
  u16* kfr   = qfr + 1048576;           // [8][32][2][4][64][8]
  u16* vfr   = kfr + 1048576;           // [8][32][4][2][64][8]

  wt_kernel<<<dim3(48), dim3(256), 0, stream>>>(Wq, Wk, Wv, wfrag);
  qkv_kernel<<<dim3(256), dim3(512), 0, stream>>>(x, wfrag, qfr, kfr, vfr);
  attn_kernel<<<dim3(8, 128), dim3(256), 0, stream>>>(qfr, kfr, vfr, out);
}

// Round 21
// 35.342 us; speedup vs baseline: 1.2486x; 1.2486x over previous
//
#include <hip/hip_runtime.h>
#include <stdint.h>

typedef unsigned short u16;
typedef __attribute__((ext_vector_type(8))) short short8;
typedef __attribute__((ext_vector_type(4))) float f32x4;
typedef __attribute__((ext_vector_type(16))) float f32x16;

#define B_ 8
#define T_ 2048
#define C_ 1024
#define D_ 64
#define PSC 0.04508422f  /* C^-0.5 * log2(e) */

__device__ inline uint32_t pack2(float lo, float hi) {
  uint32_t r;
  asm("v_cvt_pk_bf16_f32 %0, %1, %2" : "=v"(r) : "v"(lo), "v"(hi));
  return r;
}
__device__ inline u16 f2bf(float f) {
  uint32_t r;
  asm("v_cvt_pk_bf16_f32 %0, %1, %2" : "=v"(r) : "v"(f), "v"(f));
  return (u16)r;
}

// ---------------- kernel 0: W [1024][64] f32 -> B-fragment-order bf16 ------
__global__ __launch_bounds__(256) void wt_kernel(const float* __restrict__ Wq,
                                                 const float* __restrict__ Wk,
                                                 const float* __restrict__ Wv,
                                                 u16* __restrict__ wfrag) {
  const int mi = blockIdx.x >> 4;
  const int k0 = (blockIdx.x & 15) * 64;
  const float* W = (mi == 0) ? Wq : ((mi == 1) ? Wk : Wv);
  const float sc = (mi == 0) ? PSC : 1.0f;
  __shared__ u16 tr[64 * 68];

  const int t = threadIdx.x;
  {
    const int n = t & 63, kr0 = (t >> 6) * 16;
#pragma unroll
    for (int j = 0; j < 16; ++j)
      tr[n * 68 + kr0 + j] = f2bf(W[(size_t)(k0 + kr0 + j) * 64 + n] * sc);
  }
  __syncthreads();
  {
    const int n = t >> 2, q16 = (t & 3) * 16;
    const int n16g = mi * 4 + (n >> 4);
#pragma unroll
    for (int h = 0; h < 2; ++h) {
      const int kr = q16 + h * 8;
      const int kchunk = (k0 + kr) >> 5;
      const int lane = (n & 15) + 16 * ((kr >> 3) & 3);
      uint32_t pk[4];
#pragma unroll
      for (int jj = 0; jj < 4; ++jj)
        pk[jj] = (uint32_t)tr[n * 68 + kr + 2 * jj] | ((uint32_t)tr[n * 68 + kr + 2 * jj + 1] << 16);
      *(uint4*)&wfrag[(((size_t)n16g * 32 + kchunk) * 64 + lane) * 8] = *(uint4*)&pk[0];
    }
  }
}

// ---------------- kernel A: QKV projection, BM=64, register-held W ---------
// 256 blocks x 512 thr (8 waves: wh=w&1 row-half, ng=w>>1 N-group).
// Double-buffered 8KB x tiles, reg W double-buffer, 2 barriers per 2 kt.
// launch_bounds(512,1): 1 block/CU, full register freedom for the pipeline.
__global__ __launch_bounds__(512, 1) void qkv_kernel(const float* __restrict__ x,
                                                     const u16* __restrict__ wfrag,
                                                     u16* __restrict__ qfr,
                                                     u16* __restrict__ kfr,
                                                     u16* __restrict__ vfr) {
  __shared__ __align__(16) u16 xl[2][64 * 64];  // 2 x 8 KB

  const int tid = threadIdx.x;
  const int w = tid >> 6, l = tid & 63;
  const int lo16 = l & 15, hi4 = l >> 4;
  const int wh = w & 1, ng = w >> 1;
  const int m0 = blockIdx.x * 64;

  const int xrow = tid >> 3;        // 0..63
  const int xc8 = tid & 7;
  const float* xs0 = x + (size_t)(m0 + xrow) * C_ + xc8 * 8;
  u16* xdst0 = &xl[0][xrow * 64 + ((xc8 ^ (xrow & 7)) << 3)];
  u16* xdst1 = &xl[1][xrow * 64 + ((xc8 ^ (xrow & 7)) << 3)];

  f32x4 acc[2][3];
#pragma unroll
  for (int rf = 0; rf < 2; ++rf)
#pragma unroll
    for (int j = 0; j < 3; ++j) acc[rf][j] = {0.f, 0.f, 0.f, 0.f};

  const u16* wbase = wfrag + (size_t)(ng * 3) * 32 * 512 + l * 8;
  short8 wA[6], wB[6];
  float4 xr1a, xr1b, xr2a, xr2b;

#define LOADW(DST, KT)                                                        \
  _Pragma("unroll")                                                           \
  for (int i = 0; i < 6; ++i)                                                 \
    DST[i] = *(const short8*)(wbase + ((i >> 1) * 32 + (KT) * 2 + (i & 1)) * 512);

#define PACKX(A0, A1, DST)                                                    \
  { uint32_t p[4] = {pack2(A0.x, A0.y), pack2(A0.z, A0.w),                    \
                     pack2(A1.x, A1.y), pack2(A1.z, A1.w)};                   \
    *(uint4*)DST = *(uint4*)&p[0]; }

#define MFMA6(XR, WC)                                                         \
  _Pragma("unroll")                                                           \
  for (int k32 = 0; k32 < 2; ++k32) {                                         \
    const int ac = k32 * 4 + hi4;                                             \
    _Pragma("unroll")                                                         \
    for (int rf = 0; rf < 2; ++rf) {                                          \
      const int arow = wh * 32 + rf * 16 + lo16;                              \
      short8 a = *(const short8*)&XR[arow * 64 + ((ac ^ (arow & 7)) << 3)];   \
      _Pragma("unroll")                                                       \
      for (int j = 0; j < 3; ++j)                                             \
        acc[rf][j] = __builtin_amdgcn_mfma_f32_16x16x32_bf16(a, WC[j * 2 + k32], acc[rf][j], 0, 0, 0); \
    }                                                                         \
  }

  {
    float4 f0 = *(const float4*)(xs0 + 0);
    float4 f1 = *(const float4*)(xs0 + 4);
    PACKX(f0, f1, xdst0)
    xr1a = *(const float4*)(xs0 + 64);
    xr1b = *(const float4*)(xs0 + 68);
    LOADW(wA, 0)
  }
  __syncthreads();

#pragma unroll 1
  for (int kt = 0; kt < 14; kt += 2) {
    xr2a = *(const float4*)(xs0 + (kt + 2) * 64);
    xr2b = *(const float4*)(xs0 + (kt + 2) * 64 + 4);
    LOADW(wB, kt + 1)
    MFMA6(xl[0], wA)
    PACKX(xr1a, xr1b, xdst1)
    __syncthreads();
    xr1a = *(const float4*)(xs0 + (kt + 3) * 64);
    xr1b = *(const float4*)(xs0 + (kt + 3) * 64 + 4);
    LOADW(wA, kt + 2)
    MFMA6(xl[1], wB)
    PACKX(xr2a, xr2b, xdst0)
    __syncthreads();
  }
  LOADW(wB, 15)
  MFMA6(xl[0], wA)
  PACKX(xr1a, xr1b, xdst1)
  __syncthreads();
  MFMA6(xl[1], wB)
#undef LOADW
#undef PACKX
#undef MFMA6

  // ---- epilogue: scatter into fragment layouts (PSC already in Wq) ----
  const int bb = m0 >> 11;
  const int tok_b = m0 & 2047;
#pragma unroll
  for (int rf = 0; rf < 2; ++rf) {
    const int row0 = wh * 32 + rf * 16 + hi4 * 4;
    const int tok0 = tok_b + row0;
    const int tt = tok0 >> 6;
    const int t32 = tok0 >> 5;
#pragma unroll
    for (int j = 0; j < 3; ++j) {
      const int cb = ng * 48 + j * 16;
      const int mt = cb >> 6;
      const int col = (cb & 63) + lo16;
      if (mt == 0) {
        const int cs = col >> 4;
        const int lane0 = (tok0 & 31) + 32 * ((col >> 3) & 1);
        u16* qp = qfr + ((((size_t)bb * 64 + t32) * 4 + cs) * 64 + lane0) * 8 + (col & 7);
#pragma unroll
        for (int r = 0; r < 4; ++r) qp[(size_t)r * 8] = f2bf(acc[rf][j][r]);
      } else if (mt == 1) {
        const int h = (tok0 >> 5) & 1;
        const int cs = col >> 4;
        const int lane0 = (tok0 & 31) + 32 * ((col >> 3) & 1);
        u16* kp = kfr + (((((size_t)bb * 32 + tt) * 2 + h) * 4 + cs) * 64 + lane0) * 8 + (col & 7);
#pragma unroll
        for (int r = 0; r < 4; ++r) kp[(size_t)r * 8] = f2bf(acc[rf][j][r]);
      } else {
        const int ks = (tok0 >> 4) & 3;
        const int hi = (tok0 >> 3) & 1;
        const int jj = tok0 & 7;
        const int lane = (col & 31) + 32 * hi;
        const int df = col >> 5;
        uint2 st = {pack2(acc[rf][j][0], acc[rf][j][1]), pack2(acc[rf][j][2], acc[rf][j][3])};
        *(uint2*)&vfr[((((((size_t)bb * 32 + tt) * 4 + ks) * 2 + df) * 64 + lane) * 8 + jj)] = st;
      }
    }
  }
}

// ---------------- kernel B: causal flash attention (frozen R9 form) --------
__global__ __launch_bounds__(256, 2) void attn_kernel(const u16* __restrict__ qfr,
                                                      const u16* __restrict__ kfr,
                                                      const u16* __restrict__ vfr,
                                                      float* __restrict__ out) {
  __shared__ float o_lds[4][32][68];
  __shared__ float l_lds[4][64];

  const int tid = threadIdx.x;
  const int w = tid >> 6, l = tid & 63;
  const int l31 = l & 31, hi1 = l >> 5;
  const int b = blockIdx.x;
  const int y = blockIdx.y;
  const int qt = (y < 32) ? (63 - 2 * y) : (2 * (y - 32));
  const int qbase = qt * 32;
  const int boff = b * T_;
  const int NT = (qt + 2) >> 1;

  short8 qf[4];
  {
    const u16* qp = qfr + (size_t)(b * 64 + qt) * 4 * 512 + l * 8;
#pragma unroll
    for (int cs = 0; cs < 4; ++cs) qf[cs] = *(const short8*)(qp + cs * 512);
  }

  const u16* kfb = kfr + (size_t)b * 32 * 4096 + l * 8;
  const u16* vfb = vfr + (size_t)b * 32 * 4096 + l * 8;

  f32x16 O0, O1;
#pragma unroll
  for (int r = 0; r < 16; ++r) { O0[r] = 0.f; O1[r] = 0.f; }
  float lsum = 0.f;

  short8 kf[2][4];
#define LOADK(T) { const u16* kp = kfb + (size_t)(T) * 4096; \
  _Pragma("unroll") for (int h2 = 0; h2 < 2; ++h2) \
  _Pragma("unroll") for (int cs = 0; cs < 4; ++cs) \
    kf[h2][cs] = *(const short8*)(kp + (h2 * 4 + cs) * 512); }

  if (w < NT) LOADK(w);

  union { uint32_t u[4]; short8 v; } pu;
  short8 pa[4];

#pragma unroll 1
  for (int t = w; t < NT; t += 4) {
    const int k0 = t * 64;

    short8 vf[4][2];
    {
      const u16* vp = vfb + (size_t)t * 4096;
#pragma unroll
      for (int ks = 0; ks < 4; ++ks)
#pragma unroll
        for (int df = 0; df < 2; ++df)
          vf[ks][df] = *(const short8*)(vp + (ks * 2 + df) * 512);
    }

    f32x16 s0, s1, s0b, s1b;
#pragma unroll
    for (int r = 0; r < 16; ++r) { s0[r] = 0.f; s1[r] = 0.f; s0b[r] = 0.f; s1b[r] = 0.f; }
    __builtin_amdgcn_s_setprio(1);
#pragma unroll
    for (int cs = 0; cs < 2; ++cs) {
      s0 = __builtin_amdgcn_mfma_f32_32x32x16_bf16(kf[0][cs], qf[cs], s0, 0, 0, 0);
      s1 = __builtin_amdgcn_mfma_f32_32x32x16_bf16(kf[1][cs], qf[cs], s1, 0, 0, 0);
      s0b = __builtin_amdgcn_mfma_f32_32x32x16_bf16(kf[0][cs + 2], qf[cs + 2], s0b, 0, 0, 0);
      s1b = __builtin_amdgcn_mfma_f32_32x32x16_bf16(kf[1][cs + 2], qf[cs + 2], s1b, 0, 0, 0);
    }
    __builtin_amdgcn_s_setprio(0);
#pragma unroll
    for (int r = 0; r < 16; ++r) { s0[r] += s0b[r]; s1[r] += s1b[r]; }

    if (t + 4 < NT) LOADK(t + 4);

    if (k0 + 63 > qbase) {
#pragma unroll
      for (int r = 0; r < 16; ++r) {
        const int kr = (r & 3) + 8 * (r >> 2) + 4 * hi1;
        if (k0 + kr > qbase + l31) s0[r] = -1e30f;
        if (k0 + 32 + kr > qbase + l31) s1[r] = -1e30f;
      }
    }

    float p0[16], p1[16];
    float ts[4] = {0.f, 0.f, 0.f, 0.f};
#pragma unroll
    for (int r = 0; r < 16; ++r) {
      p0[r] = exp2f(s0[r]);
      p1[r] = exp2f(s1[r]);
      ts[r & 3] += p0[r] + p1[r];
    }
    lsum += (ts[0] + ts[1]) + (ts[2] + ts[3]);

#define REDIST(KS, ARR) { \
    const int s8 = ((KS) & 1) * 8; \
    uint32_t c0a = pack2(ARR[s8 + 0], ARR[s8 + 1]); \
    uint32_t c0b = pack2(ARR[s8 + 2], ARR[s8 + 3]); \
    uint32_t c1a = pack2(ARR[s8 + 4], ARR[s8 + 5]); \
    uint32_t c1b = pack2(ARR[s8 + 6], ARR[s8 + 7]); \
    uint32_t fa = hi1 ? c0a : c1a; \
    uint32_t fb = hi1 ? c0b : c1b; \
    uint32_t ga = __shfl_xor(fa, 32); \
    uint32_t gb = __shfl_xor(fb, 32); \
    pu.u[0] = hi1 ? ga : c0a; \
    pu.u[1] = hi1 ? gb : c0b; \
    pu.u[2] = hi1 ? c1a : ga; \
    pu.u[3] = hi1 ? c1b : gb; \
    pa[KS] = pu.v; }
    REDIST(0, p0)
    REDIST(1, p0)
    REDIST(2, p1)
    REDIST(3, p1)
#undef REDIST

    __builtin_amdgcn_s_setprio(1);
#pragma unroll
    for (int ks = 0; ks < 4; ++ks) {
      O0 = __builtin_amdgcn_mfma_f32_32x32x16_bf16(pa[ks], vf[ks][0], O0, 0, 0, 0);
      O1 = __builtin_amdgcn_mfma_f32_32x32x16_bf16(pa[ks], vf[ks][1], O1, 0, 0, 0);
    }
    __builtin_amdgcn_s_setprio(0);
  }
#undef LOADK

#pragma unroll
  for (int r = 0; r < 16; ++r) {
    const int qr = (r & 3) + 8 * (r >> 2) + 4 * hi1;
    o_lds[w][qr][l31] = O0[r];
    o_lds[w][qr][32 + l31] = O1[r];
  }
  l_lds[w][l] = lsum;
  __syncthreads();

  {
    const int q = tid >> 3;
    const int d8 = (tid & 7) * 8;
    float lacc = 0.f;
    float oacc[8] = {0.f, 0.f, 0.f, 0.f, 0.f, 0.f, 0.f, 0.f};
#pragma unroll
    for (int s = 0; s < 4; ++s) {
      lacc += l_lds[s][q] + l_lds[s][q + 32];
#pragma unroll
      for (int j = 0; j < 8; ++j) oacc[j] += o_lds[s][q][d8 + j];
    }
    const float inv = 1.f / lacc;
    float4 r0 = {oacc[0] * inv, oacc[1] * inv, oacc[2] * inv, oacc[3] * inv};
    float4 r1 = {oacc[4] * inv, oacc[5] * inv, oacc[6] * inv, oacc[7] * inv};
    float* op = out + (size_t)(boff + qbase + q) * 64 + d8;
    *(float4*)(op + 0) = r0;
    *(float4*)(op + 4) = r1;
  }
}

extern "C" void kernel_launch(void* const* d_in, const int* in_sizes, int n_in,
                              void* d_out, int out_size, void* d_ws, size_t ws_size,
                              hipStream_t stream) {
  const float* x  = (const float*)d_in[0];
  const float* Wq = (const float*)d_in[1];
  const float* Wk = (const float*)d_in[2];
  const float* Wv = (const float*)d_in[3];
  float* out = (float*)d_out;

  u16* ws    = (u16*)d_ws;
  u16* wfrag = ws;                      // [12][32][64][8] (Wq slice PSC-scaled)
  u16* qfr   = ws + 196608;             // [8][64][4][64][8]
  u16* kfr   = qfr + 1048576;           // [8][32][2][4][64][8]
  u16* vfr   = kfr + 1048576;           // [8][32][4][2][64][8]

  wt_kernel<<<dim3(48), dim3(256), 0, stream>>>(Wq, Wk, Wv, wfrag);
  qkv_kernel<<<dim3(256), dim3(512), 0, stream>>>(x, wfrag, qfr, kfr, vfr);
  attn_kernel<<<dim3(8, 64), dim3(256), 0, stream>>>(qfr, kfr, vfr, out);
}